// Round 1
// baseline (217.731 us; speedup 1.0000x reference)
//
#include <hip/hip_runtime.h>
#include <hip/hip_bf16.h>

typedef __attribute__((ext_vector_type(8))) short bf16x8;
typedef __attribute__((ext_vector_type(4))) float f32x4;
typedef __attribute__((ext_vector_type(4))) short s16x4;

#define M_DIM 4096   // B*S = 2*2048
#define N_DIM 4096   // D_out
#define K_DIM 4096   // D_in
#define R_DIM 4

__device__ __forceinline__ short to_bf16(float f) {
    __hip_bfloat16 h = __float2bfloat16(f);
    return *reinterpret_cast<short*>(&h);
}

// ---------------------------------------------------------------------------
// Kernel 1: tB[r][i] = tanh(scale_B[r,i]); tAg[o][r] = tanh(scale_A[o,r])*g[r]
// ---------------------------------------------------------------------------
__global__ __launch_bounds__(256)
void k_prep(const float* __restrict__ sA, const float* __restrict__ sB,
            const float* __restrict__ g, float* __restrict__ tB,
            float* __restrict__ tAg) {
    int i = blockIdx.x * 256 + threadIdx.x;
    if (i < R_DIM * K_DIM) {
        tB[i] = tanhf(sB[i]);
    } else {
        int j = i - R_DIM * K_DIM;   // j = o*4 + r
        tAg[j] = tanhf(sA[j]) * g[j & 3];
    }
}

// ---------------------------------------------------------------------------
// Kernel 2: W_eff[o,i] = weight[o,i] * sum_r tAg[o,r]*tB[r,i]  -> bf16
// One block per output row o; 256 threads x 4 float4 iterations.
// ---------------------------------------------------------------------------
__global__ __launch_bounds__(256)
void k_weff(const float* __restrict__ w, const float* __restrict__ tB,
            const float* __restrict__ tAg, __hip_bfloat16* __restrict__ weff) {
    const int o = blockIdx.x;
    const float a0 = tAg[o * 4 + 0];
    const float a1 = tAg[o * 4 + 1];
    const float a2 = tAg[o * 4 + 2];
    const float a3 = tAg[o * 4 + 3];
#pragma unroll
    for (int it = 0; it < 4; ++it) {
        const int i = (it * 256 + (int)threadIdx.x) << 2;
        float4 wv = *(const float4*)&w[(size_t)o * K_DIM + i];
        float4 b0 = *(const float4*)&tB[0 * K_DIM + i];
        float4 b1 = *(const float4*)&tB[1 * K_DIM + i];
        float4 b2 = *(const float4*)&tB[2 * K_DIM + i];
        float4 b3 = *(const float4*)&tB[3 * K_DIM + i];
        float s0 = a0 * b0.x + a1 * b1.x + a2 * b2.x + a3 * b3.x;
        float s1 = a0 * b0.y + a1 * b1.y + a2 * b2.y + a3 * b3.y;
        float s2 = a0 * b0.z + a1 * b1.z + a2 * b2.z + a3 * b3.z;
        float s3 = a0 * b0.w + a1 * b1.w + a2 * b2.w + a3 * b3.w;
        s16x4 pk;
        pk[0] = to_bf16(wv.x * s0);
        pk[1] = to_bf16(wv.y * s1);
        pk[2] = to_bf16(wv.z * s2);
        pk[3] = to_bf16(wv.w * s3);
        *(s16x4*)&weff[(size_t)o * K_DIM + i] = pk;
    }
}

// ---------------------------------------------------------------------------
// Kernel 3: out[m, n] = sum_k x_bf16[m,k] * weff[n,k] + bias[n]
// 128x128 tile, BK=64, 4 waves (2x2), each wave 64x64 = 4x4 frags of
// mfma_f32_16x16x32_bf16.  B staged via global_load_lds (16B) with
// involution XOR-swizzle; A reg-staged f32->bf16 into padded LDS.
// ---------------------------------------------------------------------------
__global__ __launch_bounds__(256)
void k_gemm(const float* __restrict__ x, const __hip_bfloat16* __restrict__ weff,
            const float* __restrict__ bias, float* __restrict__ out) {
    __shared__ short As[128 * 72];   // padded stride 72 elems (144B): 2-way max
    __shared__ short Bs[128 * 64];   // linear, XOR-swizzled content

    const int tid  = threadIdx.x;
    const int lane = tid & 63;
    const int wid  = tid >> 6;
    const int wr   = wid >> 1;   // wave row (0..1)
    const int wc   = wid & 1;    // wave col (0..1)

    // XCD-aware bijective swizzle: nwg=1024, 1024 % 8 == 0
    const int bid = blockIdx.x;
    const int swz = (bid & 7) * 128 + (bid >> 3);
    const int m0  = (swz >> 5) << 7;   // block row base
    const int n0  = (swz & 31) << 7;   // block col base

    f32x4 acc[4][4] = {};

    for (int kt = 0; kt < K_DIM / 64; ++kt) {
        const int k0 = kt * 64;
        __syncthreads();   // previous iter's readers done before overwrite

        // ---- B tile: weff[n0..n0+127][k0..k0+63] -> Bs, direct-to-LDS ----
        // Physical LDS is linear in (pass, wave, lane); global source is
        // pre-swizzled so that reads XOR with the same involution.
#pragma unroll
        for (int p = 0; p < 4; ++p) {
            const int P    = p * 4096 + wid * 1024 + lane * 16;  // phys byte
            const int row  = P >> 7;                              // 128B/row
            const int colb = (P & 127) ^ ((row & 7) << 4);        // logical col bytes
            const __hip_bfloat16* gsrc =
                weff + ((size_t)(n0 + row) << 12) + (k0 + (colb >> 1));
            __builtin_amdgcn_global_load_lds(
                (const __attribute__((address_space(1))) void*)gsrc,
                (__attribute__((address_space(3))) void*)&Bs[p * 2048 + wid * 512],
                16, 0, 0);
        }

        // ---- A tile: x f32 -> bf16 -> As (padded) ----
#pragma unroll
        for (int c = 0; c < 4; ++c) {
            const int id  = c * 256 + tid;       // 0..1023
            const int row = id >> 3;             // 0..127
            const int col = (id & 7) << 3;       // 0,8,...,56
            const float* src = x + (size_t)(m0 + row) * K_DIM + (k0 + col);
            float4 u = *(const float4*)src;
            float4 v = *(const float4*)(src + 4);
            bf16x8 pk;
            pk[0] = to_bf16(u.x); pk[1] = to_bf16(u.y);
            pk[2] = to_bf16(u.z); pk[3] = to_bf16(u.w);
            pk[4] = to_bf16(v.x); pk[5] = to_bf16(v.y);
            pk[6] = to_bf16(v.z); pk[7] = to_bf16(v.w);
            *(bf16x8*)&As[row * 72 + col] = pk;
        }

        __syncthreads();   // compiler drains vmcnt/lgkmcnt before barrier

        // ---- compute: 2 K-subtiles of 32, 16 MFMA each ----
#pragma unroll
        for (int kk = 0; kk < 2; ++kk) {
            const int ac = kk * 32 + ((lane >> 4) << 3);  // elem col in [0,64)
            bf16x8 af[4], bf[4];
            const int ar = wr * 64 + (lane & 15);
#pragma unroll
            for (int m = 0; m < 4; ++m)
                af[m] = *(const bf16x8*)&As[(ar + m * 16) * 72 + ac];
            const int br = wc * 64 + (lane & 15);
#pragma unroll
            for (int n = 0; n < 4; ++n) {
                const int row  = br + n * 16;
                const int byte = ((row << 7) + (ac << 1)) ^ ((row & 7) << 4);
                bf[n] = *(const bf16x8*)((const char*)Bs + byte);
            }
#pragma unroll
            for (int m = 0; m < 4; ++m)
#pragma unroll
                for (int n = 0; n < 4; ++n)
                    acc[m][n] = __builtin_amdgcn_mfma_f32_16x16x32_bf16(
                        af[m], bf[n], acc[m][n], 0, 0, 0);
        }
    }

    // ---- epilogue: C/D map col=lane&15, row=(lane>>4)*4+j ----
#pragma unroll
    for (int n = 0; n < 4; ++n) {
        const int col = n0 + wc * 64 + n * 16 + (lane & 15);
        const float bv = bias[col];
#pragma unroll
        for (int m = 0; m < 4; ++m) {
            const int rbase = m0 + wr * 64 + m * 16 + ((lane >> 4) << 2);
#pragma unroll
            for (int j = 0; j < 4; ++j)
                out[(size_t)(rbase + j) * N_DIM + col] = acc[m][n][j] + bv;
        }
    }
}

// ---------------------------------------------------------------------------
extern "C" void kernel_launch(void* const* d_in, const int* in_sizes, int n_in,
                              void* d_out, int out_size, void* d_ws, size_t ws_size,
                              hipStream_t stream) {
    const float* x    = (const float*)d_in[0];  // [2,2048,4096]
    const float* w    = (const float*)d_in[1];  // [4096,4096]
    const float* bias = (const float*)d_in[2];  // [4096]
    const float* sA   = (const float*)d_in[3];  // [4096,4]
    const float* sB   = (const float*)d_in[4];  // [4,4096]
    const float* g    = (const float*)d_in[5];  // [4]
    float* out = (float*)d_out;

    // workspace layout: [weff bf16: 32MB][tB f32: 64KB][tAg f32: 64KB]
    __hip_bfloat16* weff = (__hip_bfloat16*)d_ws;
    float* tB  = (float*)((char*)d_ws + (32u << 20));
    float* tAg = (float*)((char*)d_ws + (32u << 20) + (R_DIM * K_DIM * 4));

    k_prep<<<dim3((2 * R_DIM * K_DIM) / 256), dim3(256), 0, stream>>>(sA, sB, g, tB, tAg);
    k_weff<<<dim3(N_DIM), dim3(256), 0, stream>>>(w, tB, tAg, weff);
    k_gemm<<<dim3((M_DIM / 128) * (N_DIM / 128)), dim3(256), 0, stream>>>(x, weff, bias, out);
}

// Round 2
// 198.081 us; speedup vs baseline: 1.0992x; 1.0992x over previous
//
#include <hip/hip_runtime.h>
#include <hip/hip_bf16.h>

typedef __attribute__((ext_vector_type(8))) short bf16x8;
typedef __attribute__((ext_vector_type(4))) float f32x4;
typedef __attribute__((ext_vector_type(4))) short s16x4;

#define M_DIM 4096   // B*S = 2*2048
#define N_DIM 4096   // D_out
#define K_DIM 4096   // D_in
#define R_DIM 4

__device__ __forceinline__ short to_bf16(float f) {
    __hip_bfloat16 h = __float2bfloat16(f);
    return *reinterpret_cast<short*>(&h);
}

// ---------------------------------------------------------------------------
// Kernel 1: tB[r][i] = tanh(scale_B[r,i]); tAg[o][r] = tanh(scale_A[o,r])*g[r]
// ---------------------------------------------------------------------------
__global__ __launch_bounds__(256)
void k_prep(const float* __restrict__ sA, const float* __restrict__ sB,
            const float* __restrict__ g, float* __restrict__ tB,
            float* __restrict__ tAg) {
    int i = blockIdx.x * 256 + threadIdx.x;
    if (i < R_DIM * K_DIM) {
        tB[i] = tanhf(sB[i]);
    } else {
        int j = i - R_DIM * K_DIM;   // j = o*4 + r
        tAg[j] = tanhf(sA[j]) * g[j & 3];
    }
}

// ---------------------------------------------------------------------------
// Kernel 2: x_bf16[m,k] = (bf16) x[m,k]   (16M elements, 8/thread)
// ---------------------------------------------------------------------------
__global__ __launch_bounds__(256)
void k_xcast(const float* __restrict__ x, __hip_bfloat16* __restrict__ xb) {
    const size_t i = ((size_t)blockIdx.x * 256 + threadIdx.x) << 3;
    float4 u = *(const float4*)&x[i];
    float4 v = *(const float4*)&x[i + 4];
    bf16x8 pk;
    pk[0] = to_bf16(u.x); pk[1] = to_bf16(u.y);
    pk[2] = to_bf16(u.z); pk[3] = to_bf16(u.w);
    pk[4] = to_bf16(v.x); pk[5] = to_bf16(v.y);
    pk[6] = to_bf16(v.z); pk[7] = to_bf16(v.w);
    *(bf16x8*)&xb[i] = pk;
}

// ---------------------------------------------------------------------------
// Kernel 3: W_eff[o,i] = weight[o,i] * sum_r tAg[o,r]*tB[r,i]  -> bf16
// ---------------------------------------------------------------------------
__global__ __launch_bounds__(256)
void k_weff(const float* __restrict__ w, const float* __restrict__ tB,
            const float* __restrict__ tAg, __hip_bfloat16* __restrict__ weff) {
    const int o = blockIdx.x;
    const float a0 = tAg[o * 4 + 0];
    const float a1 = tAg[o * 4 + 1];
    const float a2 = tAg[o * 4 + 2];
    const float a3 = tAg[o * 4 + 3];
#pragma unroll
    for (int it = 0; it < 4; ++it) {
        const int i = (it * 256 + (int)threadIdx.x) << 2;
        float4 wv = *(const float4*)&w[(size_t)o * K_DIM + i];
        float4 b0 = *(const float4*)&tB[0 * K_DIM + i];
        float4 b1 = *(const float4*)&tB[1 * K_DIM + i];
        float4 b2 = *(const float4*)&tB[2 * K_DIM + i];
        float4 b3 = *(const float4*)&tB[3 * K_DIM + i];
        float s0 = a0 * b0.x + a1 * b1.x + a2 * b2.x + a3 * b3.x;
        float s1 = a0 * b0.y + a1 * b1.y + a2 * b2.y + a3 * b3.y;
        float s2 = a0 * b0.z + a1 * b1.z + a2 * b2.z + a3 * b3.z;
        float s3 = a0 * b0.w + a1 * b1.w + a2 * b2.w + a3 * b3.w;
        s16x4 pk;
        pk[0] = to_bf16(wv.x * s0);
        pk[1] = to_bf16(wv.y * s1);
        pk[2] = to_bf16(wv.z * s2);
        pk[3] = to_bf16(wv.w * s3);
        *(s16x4*)&weff[(size_t)o * K_DIM + i] = pk;
    }
}

// ---------------------------------------------------------------------------
// Kernel 4 (fast path): out = x_bf16 @ weff^T + bias
// m97 structure: 128x128 tile, BK=64, 4 waves (2x2), each wave 64x64 via
// 4x4 frags of mfma_f32_16x16x32_bf16. BOTH operands staged with
// global_load_lds width=16 + involution XOR-swizzle (pre-swizzled source,
// swizzled ds_read — rule #21 both-sides).
// ---------------------------------------------------------------------------
__global__ __launch_bounds__(256)
void k_gemm_bf16a(const __hip_bfloat16* __restrict__ xb,
                  const __hip_bfloat16* __restrict__ weff,
                  const float* __restrict__ bias, float* __restrict__ out) {
    __shared__ short As[128 * 64];   // linear phys, XOR-swizzled content
    __shared__ short Bs[128 * 64];

    const int tid  = threadIdx.x;
    const int lane = tid & 63;
    const int wid  = tid >> 6;
    const int wr   = wid >> 1;   // wave row (0..1)
    const int wc   = wid & 1;    // wave col (0..1)

    // XCD-aware bijective swizzle: nwg=1024, 1024 % 8 == 0
    const int bid = blockIdx.x;
    const int swz = (bid & 7) * 128 + (bid >> 3);
    const int m0  = (swz >> 5) << 7;   // block row base
    const int n0  = (swz & 31) << 7;   // block col base

    f32x4 acc[4][4] = {};

    // per-lane phys position for staging (constant across k-tiles)
    const int P    = wid * 1024 + lane * 16;          // phys byte within pass
    const int prow = P >> 7;                          // row contribution 0..7
    // logical col bytes for this lane at pass p: ((P&127) ^ (((prow+32p)&7)<<4))
    // note (prow + 32p) & 7 == prow & 7  (32p ≡ 0 mod 8)
    const int colb = (P & 127) ^ ((prow & 7) << 4);

    for (int kt = 0; kt < K_DIM / 64; ++kt) {
        const int k0 = kt * 64;
        __syncthreads();   // previous iter's readers done before overwrite

#pragma unroll
        for (int p = 0; p < 4; ++p) {
            const int row = p * 32 + prow;
            const __hip_bfloat16* ga =
                xb + ((size_t)(m0 + row) << 12) + (k0 + (colb >> 1));
            __builtin_amdgcn_global_load_lds(
                (const __attribute__((address_space(1))) void*)ga,
                (__attribute__((address_space(3))) void*)&As[p * 2048 + wid * 512],
                16, 0, 0);
            const __hip_bfloat16* gb =
                weff + ((size_t)(n0 + row) << 12) + (k0 + (colb >> 1));
            __builtin_amdgcn_global_load_lds(
                (const __attribute__((address_space(1))) void*)gb,
                (__attribute__((address_space(3))) void*)&Bs[p * 2048 + wid * 512],
                16, 0, 0);
        }

        __syncthreads();   // compiler drains vmcnt before barrier

#pragma unroll
        for (int kk = 0; kk < 2; ++kk) {
            const int cb = (kk * 32 + ((lane >> 4) << 3)) << 1;  // col bytes
            bf16x8 af[4], bf[4];
            const int ar = wr * 64 + (lane & 15);
#pragma unroll
            for (int m = 0; m < 4; ++m) {
                const int row  = ar + m * 16;
                const int byte = ((row << 7) + cb) ^ ((row & 7) << 4);
                af[m] = *(const bf16x8*)((const char*)As + byte);
            }
            const int br = wc * 64 + (lane & 15);
#pragma unroll
            for (int n = 0; n < 4; ++n) {
                const int row  = br + n * 16;
                const int byte = ((row << 7) + cb) ^ ((row & 7) << 4);
                bf[n] = *(const bf16x8*)((const char*)Bs + byte);
            }
#pragma unroll
            for (int m = 0; m < 4; ++m)
#pragma unroll
                for (int n = 0; n < 4; ++n)
                    acc[m][n] = __builtin_amdgcn_mfma_f32_16x16x32_bf16(
                        af[m], bf[n], acc[m][n], 0, 0, 0);
        }
    }

    // ---- epilogue: C/D map col=lane&15, row=(lane>>4)*4+j ----
#pragma unroll
    for (int n = 0; n < 4; ++n) {
        const int col = n0 + wc * 64 + n * 16 + (lane & 15);
        const float bv = bias[col];
#pragma unroll
        for (int m = 0; m < 4; ++m) {
            const int rbase = m0 + wr * 64 + m * 16 + ((lane >> 4) << 2);
#pragma unroll
            for (int j = 0; j < 4; ++j)
                out[(size_t)(rbase + j) * N_DIM + col] = acc[m][n][j] + bv;
        }
    }
}

// ---------------------------------------------------------------------------
// Fallback GEMM (round-1 verified): A reg-staged f32->bf16 into padded LDS.
// Used only if ws_size can't hold x_bf16.
// ---------------------------------------------------------------------------
__global__ __launch_bounds__(256)
void k_gemm_f32a(const float* __restrict__ x, const __hip_bfloat16* __restrict__ weff,
                 const float* __restrict__ bias, float* __restrict__ out) {
    __shared__ short As[128 * 72];
    __shared__ short Bs[128 * 64];

    const int tid  = threadIdx.x;
    const int lane = tid & 63;
    const int wid  = tid >> 6;
    const int wr   = wid >> 1;
    const int wc   = wid & 1;

    const int bid = blockIdx.x;
    const int swz = (bid & 7) * 128 + (bid >> 3);
    const int m0  = (swz >> 5) << 7;
    const int n0  = (swz & 31) << 7;

    f32x4 acc[4][4] = {};

    for (int kt = 0; kt < K_DIM / 64; ++kt) {
        const int k0 = kt * 64;
        __syncthreads();

#pragma unroll
        for (int p = 0; p < 4; ++p) {
            const int P    = p * 4096 + wid * 1024 + lane * 16;
            const int row  = P >> 7;
            const int colb = (P & 127) ^ ((row & 7) << 4);
            const __hip_bfloat16* gsrc =
                weff + ((size_t)(n0 + row) << 12) + (k0 + (colb >> 1));
            __builtin_amdgcn_global_load_lds(
                (const __attribute__((address_space(1))) void*)gsrc,
                (__attribute__((address_space(3))) void*)&Bs[p * 2048 + wid * 512],
                16, 0, 0);
        }

#pragma unroll
        for (int c = 0; c < 4; ++c) {
            const int id  = c * 256 + tid;
            const int row = id >> 3;
            const int col = (id & 7) << 3;
            const float* src = x + (size_t)(m0 + row) * K_DIM + (k0 + col);
            float4 u = *(const float4*)src;
            float4 v = *(const float4*)(src + 4);
            bf16x8 pk;
            pk[0] = to_bf16(u.x); pk[1] = to_bf16(u.y);
            pk[2] = to_bf16(u.z); pk[3] = to_bf16(u.w);
            pk[4] = to_bf16(v.x); pk[5] = to_bf16(v.y);
            pk[6] = to_bf16(v.z); pk[7] = to_bf16(v.w);
            *(bf16x8*)&As[row * 72 + col] = pk;
        }

        __syncthreads();

#pragma unroll
        for (int kk = 0; kk < 2; ++kk) {
            const int ac = kk * 32 + ((lane >> 4) << 3);
            bf16x8 af[4], bf[4];
            const int ar = wr * 64 + (lane & 15);
#pragma unroll
            for (int m = 0; m < 4; ++m)
                af[m] = *(const bf16x8*)&As[(ar + m * 16) * 72 + ac];
            const int br = wc * 64 + (lane & 15);
#pragma unroll
            for (int n = 0; n < 4; ++n) {
                const int row  = br + n * 16;
                const int byte = ((row << 7) + (ac << 1)) ^ ((row & 7) << 4);
                bf[n] = *(const bf16x8*)((const char*)Bs + byte);
            }
#pragma unroll
            for (int m = 0; m < 4; ++m)
#pragma unroll
                for (int n = 0; n < 4; ++n)
                    acc[m][n] = __builtin_amdgcn_mfma_f32_16x16x32_bf16(
                        af[m], bf[n], acc[m][n], 0, 0, 0);
        }
    }

#pragma unroll
    for (int n = 0; n < 4; ++n) {
        const int col = n0 + wc * 64 + n * 16 + (lane & 15);
        const float bv = bias[col];
#pragma unroll
        for (int m = 0; m < 4; ++m) {
            const int rbase = m0 + wr * 64 + m * 16 + ((lane >> 4) << 2);
#pragma unroll
            for (int j = 0; j < 4; ++j)
                out[(size_t)(rbase + j) * N_DIM + col] = acc[m][n][j] + bv;
        }
    }
}

// ---------------------------------------------------------------------------
extern "C" void kernel_launch(void* const* d_in, const int* in_sizes, int n_in,
                              void* d_out, int out_size, void* d_ws, size_t ws_size,
                              hipStream_t stream) {
    const float* x    = (const float*)d_in[0];  // [2,2048,4096]
    const float* w    = (const float*)d_in[1];  // [4096,4096]
    const float* bias = (const float*)d_in[2];  // [4096]
    const float* sA   = (const float*)d_in[3];  // [4096,4]
    const float* sB   = (const float*)d_in[4];  // [4,4096]
    const float* g    = (const float*)d_in[5];  // [4]
    float* out = (float*)d_out;

    const size_t fast_need = (64ull << 20) + (256u << 10);

    if (ws_size >= fast_need) {
        // [weff bf16: 32MB][x_bf16: 32MB][tB f32: 64KB][tAg f32: 64KB]
        __hip_bfloat16* weff = (__hip_bfloat16*)d_ws;
        __hip_bfloat16* xb   = (__hip_bfloat16*)((char*)d_ws + (32ull << 20));
        float* tB  = (float*)((char*)d_ws + (64ull << 20));
        float* tAg = (float*)((char*)d_ws + (64ull << 20) + (R_DIM * K_DIM * 4));

        k_prep<<<dim3((2 * R_DIM * K_DIM) / 256), dim3(256), 0, stream>>>(sA, sB, g, tB, tAg);
        k_xcast<<<dim3((M_DIM * K_DIM) / (256 * 8)), dim3(256), 0, stream>>>(x, xb);
        k_weff<<<dim3(N_DIM), dim3(256), 0, stream>>>(w, tB, tAg, weff);
        k_gemm_bf16a<<<dim3((M_DIM / 128) * (N_DIM / 128)), dim3(256), 0, stream>>>(xb, weff, bias, out);
    } else {
        // round-1 layout: [weff bf16: 32MB][tB f32: 64KB][tAg f32: 64KB]
        __hip_bfloat16* weff = (__hip_bfloat16*)d_ws;
        float* tB  = (float*)((char*)d_ws + (32ull << 20));
        float* tAg = (float*)((char*)d_ws + (32ull << 20) + (R_DIM * K_DIM * 4));

        k_prep<<<dim3((2 * R_DIM * K_DIM) / 256), dim3(256), 0, stream>>>(sA, sB, g, tB, tAg);
        k_weff<<<dim3(N_DIM), dim3(256), 0, stream>>>(w, tB, tAg, weff);
        k_gemm_f32a<<<dim3((M_DIM / 128) * (N_DIM / 128)), dim3(256), 0, stream>>>(x, weff, bias, out);
    }
}

// Round 3
// 156.230 us; speedup vs baseline: 1.3937x; 1.2679x over previous
//
#include <hip/hip_runtime.h>
#include <hip/hip_bf16.h>

typedef __attribute__((ext_vector_type(8))) short bf16x8;
typedef __attribute__((ext_vector_type(4))) float f32x4;
typedef __attribute__((ext_vector_type(4))) short s16x4;

#define M_DIM 4096   // B*S = 2*2048
#define N_DIM 4096   // D_out
#define K_DIM 4096   // D_in
#define R_DIM 4

__device__ __forceinline__ short to_bf16(float f) {
    __hip_bfloat16 h = __float2bfloat16(f);
    return *reinterpret_cast<short*>(&h);
}

// ---------------------------------------------------------------------------
// Kernel 1: tB[r][i] = tanh(scale_B[r,i]); tAg[o][r] = tanh(scale_A[o,r])*g[r]
// ---------------------------------------------------------------------------
__global__ __launch_bounds__(256)
void k_prep(const float* __restrict__ sA, const float* __restrict__ sB,
            const float* __restrict__ g, float* __restrict__ tB,
            float* __restrict__ tAg) {
    int i = blockIdx.x * 256 + threadIdx.x;
    if (i < R_DIM * K_DIM) {
        tB[i] = tanhf(sB[i]);
    } else {
        int j = i - R_DIM * K_DIM;   // j = o*4 + r
        tAg[j] = tanhf(sA[j]) * g[j & 3];
    }
}

// ---------------------------------------------------------------------------
// Kernel 2: x_bf16[m,k] = (bf16) x[m,k]
// ---------------------------------------------------------------------------
__global__ __launch_bounds__(256)
void k_xcast(const float* __restrict__ x, __hip_bfloat16* __restrict__ xb) {
    const size_t i = ((size_t)blockIdx.x * 256 + threadIdx.x) << 3;
    float4 u = *(const float4*)&x[i];
    float4 v = *(const float4*)&x[i + 4];
    bf16x8 pk;
    pk[0] = to_bf16(u.x); pk[1] = to_bf16(u.y);
    pk[2] = to_bf16(u.z); pk[3] = to_bf16(u.w);
    pk[4] = to_bf16(v.x); pk[5] = to_bf16(v.y);
    pk[6] = to_bf16(v.z); pk[7] = to_bf16(v.w);
    *(bf16x8*)&xb[i] = pk;
}

// ---------------------------------------------------------------------------
// Kernel 3: W_eff[o,i] = weight[o,i] * sum_r tAg[o,r]*tB[r,i]  -> bf16
// ---------------------------------------------------------------------------
__global__ __launch_bounds__(256)
void k_weff(const float* __restrict__ w, const float* __restrict__ tB,
            const float* __restrict__ tAg, __hip_bfloat16* __restrict__ weff) {
    const int o = blockIdx.x;
    const float a0 = tAg[o * 4 + 0];
    const float a1 = tAg[o * 4 + 1];
    const float a2 = tAg[o * 4 + 2];
    const float a3 = tAg[o * 4 + 3];
#pragma unroll
    for (int it = 0; it < 4; ++it) {
        const int i = (it * 256 + (int)threadIdx.x) << 2;
        float4 wv = *(const float4*)&w[(size_t)o * K_DIM + i];
        float4 b0 = *(const float4*)&tB[0 * K_DIM + i];
        float4 b1 = *(const float4*)&tB[1 * K_DIM + i];
        float4 b2 = *(const float4*)&tB[2 * K_DIM + i];
        float4 b3 = *(const float4*)&tB[3 * K_DIM + i];
        float s0 = a0 * b0.x + a1 * b1.x + a2 * b2.x + a3 * b3.x;
        float s1 = a0 * b0.y + a1 * b1.y + a2 * b2.y + a3 * b3.y;
        float s2 = a0 * b0.z + a1 * b1.z + a2 * b2.z + a3 * b3.z;
        float s3 = a0 * b0.w + a1 * b1.w + a2 * b2.w + a3 * b3.w;
        s16x4 pk;
        pk[0] = to_bf16(wv.x * s0);
        pk[1] = to_bf16(wv.y * s1);
        pk[2] = to_bf16(wv.z * s2);
        pk[3] = to_bf16(wv.w * s3);
        *(s16x4*)&weff[(size_t)o * K_DIM + i] = pk;
    }
}

// ---------------------------------------------------------------------------
// Kernel 4: out = x_bf16 @ weff^T + bias  — 256x256 8-phase template.
// 8 waves (2M x 4N), BK=64, LDS = 2dbuf x 2half x 128x64 bf16 x {A,B} = 128KB.
// Per phase: ds_read frags | stage 1 half-tile | barrier | lgkmcnt(0) |
// setprio(1) 16xMFMA setprio(0) | [vmcnt(4) at ph4/8] | barrier.
// Staging schedule (iter i computes K-tiles t0=2i from d0, t1=2i+1 from d1):
//   ph1: A[1][0]<-t1   ph2: A[1][1]<-t1   ph3: B[0][0]<-t0+2  ph4: B[0][1]<-t0+2
//   ph5: A[0][0]<-t0+2 ph6: A[0][1]<-t0+2 ph7: B[1][0]<-t0+3  ph8: B[1][1]<-t0+3
// Each target is freed >=1 barrier before its stage issues (A[d] free after
// ph4/ph8 MFMA-barrier; B[d] free after ph1/ph5). vmcnt(4) leaves exactly the
// last 2 staged half-tiles (4 loads) in flight.
// ---------------------------------------------------------------------------
#define MFMA_N(q, n, bA, bB) \
    acc[2*(q)][(n)]   = __builtin_amdgcn_mfma_f32_16x16x32_bf16(a0, bA, acc[2*(q)][(n)],   0, 0, 0); \
    acc[2*(q)][(n)]   = __builtin_amdgcn_mfma_f32_16x16x32_bf16(a1, bB, acc[2*(q)][(n)],   0, 0, 0); \
    acc[2*(q)+1][(n)] = __builtin_amdgcn_mfma_f32_16x16x32_bf16(a2, bA, acc[2*(q)+1][(n)], 0, 0, 0); \
    acc[2*(q)+1][(n)] = __builtin_amdgcn_mfma_f32_16x16x32_bf16(a3, bB, acc[2*(q)+1][(n)], 0, 0, 0);

#define PHASE(d, q, STAGE_STMT, WAIT_STMT) \
    { \
        const int Ab = ((d) * 2 + wr) * 8192; \
        a0 = FRAG(Ab, (2*(q))   * 16 + l15, cb0); \
        a1 = FRAG(Ab, (2*(q))   * 16 + l15, cb1); \
        a2 = FRAG(Ab, (2*(q)+1) * 16 + l15, cb0); \
        a3 = FRAG(Ab, (2*(q)+1) * 16 + l15, cb1); \
        if ((q) == 0) { \
            const int Bb = 32768 + ((d) * 2 + (wc >> 1)) * 8192; \
            b0 = FRAG(Bb, br0, cb0); b1 = FRAG(Bb, br0, cb1); \
            b2 = FRAG(Bb, br1, cb0); b3 = FRAG(Bb, br1, cb1); \
            b4 = FRAG(Bb, br2, cb0); b5 = FRAG(Bb, br2, cb1); \
            b6 = FRAG(Bb, br3, cb0); b7 = FRAG(Bb, br3, cb1); \
        } \
        STAGE_STMT; \
        __builtin_amdgcn_s_barrier(); \
        asm volatile("s_waitcnt lgkmcnt(0)" ::: "memory"); \
        __builtin_amdgcn_sched_barrier(0); \
        __builtin_amdgcn_s_setprio(1); \
        MFMA_N(q, 0, b0, b1); MFMA_N(q, 1, b2, b3); \
        MFMA_N(q, 2, b4, b5); MFMA_N(q, 3, b6, b7); \
        __builtin_amdgcn_s_setprio(0); \
        WAIT_STMT; \
        __builtin_amdgcn_s_barrier(); \
    }

__global__ __launch_bounds__(512)
void k_gemm8(const __hip_bfloat16* __restrict__ xb,
             const __hip_bfloat16* __restrict__ weff,
             const float* __restrict__ bias, float* __restrict__ out) {
    __shared__ short lds[65536];   // A halves: [0,32768) ; B halves: [32768,65536)

    const int tid  = threadIdx.x;
    const int lane = tid & 63;
    const int wid  = tid >> 6;
    const int wr   = wid >> 2;           // wave M row 0..1  (128 rows each)
    const int wc   = wid & 3;            // wave N col 0..3  (64 cols each)
    const int l15  = lane & 15;
    const int cb0  = (lane >> 4) << 4;   // ksub0 fragment col-byte
    const int cb1  = cb0 + 64;           // ksub1

    // XCD-aware bijective swizzle: nwg=256, 256 % 8 == 0
    const int bid = blockIdx.x;
    const int swz = (bid & 7) * 32 + (bid >> 3);
    const int m0g = (swz >> 4) << 8;
    const int n0g = (swz & 15) << 8;

    const int br0 = (wc & 1) * 64 + 0  + l15;
    const int br1 = (wc & 1) * 64 + 16 + l15;
    const int br2 = (wc & 1) * 64 + 32 + l15;
    const int br3 = (wc & 1) * 64 + 48 + l15;

    auto STAGE = [&](const __hip_bfloat16* __restrict__ src, int gr0, int k0, int base) {
#pragma unroll
        for (int p = 0; p < 2; ++p) {
            const int P    = p * 8192 + tid * 16;            // phys byte in half
            const int row  = P >> 7;
            const int colb = (P & 127) ^ ((row & 7) << 4);   // inverse-swizzled src
            const __hip_bfloat16* g = src + ((size_t)(gr0 + row) << 12) + (k0 + (colb >> 1));
            __builtin_amdgcn_global_load_lds(
                (const __attribute__((address_space(1))) void*)g,
                (__attribute__((address_space(3))) void*)&lds[base + (P >> 1)],
                16, 0, 0);
        }
    };

    auto FRAG = [&](int base, int row, int cb) -> bf16x8 {
        const int byte = ((((row << 7) + cb) ^ ((row & 7) << 4))) + base * 2;
        return *(const bf16x8*)((const char*)lds + byte);
    };

    f32x4 acc[8][4] = {};
    bf16x8 a0, a1, a2, a3, b0, b1, b2, b3, b4, b5, b6, b7;

    // prologue: K-tile0 A+B, K-tile1 B   (12 loads; allow B[1] in flight)
    STAGE(xb,   m0g,       0,  0);
    STAGE(xb,   m0g + 128, 0,  8192);
    STAGE(weff, n0g,       0,  32768);
    STAGE(weff, n0g + 128, 0,  40960);
    STAGE(weff, n0g,       64, 49152);
    STAGE(weff, n0g + 128, 64, 57344);
    asm volatile("s_waitcnt vmcnt(4)" ::: "memory");
    __builtin_amdgcn_s_barrier();

    for (int i = 0; i < 32; ++i) {
        const int t1k = (2 * i + 1) * 64;
        const int kA  = (2 * i + 2 < 64 ? 2 * i + 2 : 63) * 64;
        const int kB  = (2 * i + 3 < 64 ? 2 * i + 3 : 63) * 64;

        PHASE(0, 0, STAGE(xb,   m0g,       t1k, 16384), );
        PHASE(0, 1, STAGE(xb,   m0g + 128, t1k, 24576), );
        PHASE(0, 2, STAGE(weff, n0g,       kA,  32768), );
        PHASE(0, 3, STAGE(weff, n0g + 128, kA,  40960),
              asm volatile("s_waitcnt vmcnt(4)" ::: "memory"));
        PHASE(1, 0, STAGE(xb,   m0g,       kA,  0), );
        PHASE(1, 1, STAGE(xb,   m0g + 128, kA,  8192), );
        PHASE(1, 2, STAGE(weff, n0g,       kB,  49152), );
        PHASE(1, 3, STAGE(weff, n0g + 128, kB,  57344),
              asm volatile("s_waitcnt vmcnt(4)" ::: "memory"));
    }

    // epilogue: C/D map col=lane&15, row=(lane>>4)*4+j
#pragma unroll
    for (int n = 0; n < 4; ++n) {
        const int col = n0g + wc * 64 + n * 16 + l15;
        const float bv = bias[col];
#pragma unroll
        for (int m = 0; m < 8; ++m) {
            const int rbase = m0g + wr * 128 + m * 16 + ((lane >> 4) << 2);
#pragma unroll
            for (int j = 0; j < 4; ++j)
                out[(size_t)(rbase + j) * N_DIM + col] = acc[m][n][j] + bv;
        }
    }
}

// ---------------------------------------------------------------------------
extern "C" void kernel_launch(void* const* d_in, const int* in_sizes, int n_in,
                              void* d_out, int out_size, void* d_ws, size_t ws_size,
                              hipStream_t stream) {
    const float* x    = (const float*)d_in[0];  // [2,2048,4096]
    const float* w    = (const float*)d_in[1];  // [4096,4096]
    const float* bias = (const float*)d_in[2];  // [4096]
    const float* sA   = (const float*)d_in[3];  // [4096,4]
    const float* sB   = (const float*)d_in[4];  // [4,4096]
    const float* g    = (const float*)d_in[5];  // [4]
    float* out = (float*)d_out;

    // [weff bf16: 32MB][x_bf16: 32MB][tB f32: 64KB][tAg f32: 64KB]
    // (round 2 confirmed ws_size >= 64MB + 256KB: fast path ran)
    __hip_bfloat16* weff = (__hip_bfloat16*)d_ws;
    __hip_bfloat16* xb   = (__hip_bfloat16*)((char*)d_ws + (32ull << 20));
    float* tB  = (float*)((char*)d_ws + (64ull << 20));
    float* tAg = (float*)((char*)d_ws + (64ull << 20) + (R_DIM * K_DIM * 4));

    k_prep<<<dim3((2 * R_DIM * K_DIM) / 256), dim3(256), 0, stream>>>(sA, sB, g, tB, tAg);
    k_xcast<<<dim3((M_DIM * K_DIM) / (256 * 8)), dim3(256), 0, stream>>>(x, xb);
    k_weff<<<dim3(N_DIM), dim3(256), 0, stream>>>(w, tB, tAg, weff);
    k_gemm8<<<dim3((M_DIM / 256) * (N_DIM / 256)), dim3(512), 0, stream>>>(xb, weff, bias, out);
}